// Round 8
// baseline (353.562 us; speedup 1.0000x reference)
//
#include <hip/hip_runtime.h>
#include <hip/hip_bf16.h>
#include <cmath>

#define N_TOK 16384
#define D_DIM 2048
#define H_DIM 1024
#define E_DIM 64

typedef _Float16 half8 __attribute__((ext_vector_type(8)));
typedef float floatx4 __attribute__((ext_vector_type(4)));

// ---------------------------------------------------------------------------
// Transpose + split W1 [2048k][1024c] -> whT/wlT [1024c][2048k] f16.
// ---------------------------------------------------------------------------
__global__ __launch_bounds__(256) void splitT_w1_kernel(
    const float* __restrict__ W1, _Float16* __restrict__ whT,
    _Float16* __restrict__ wlT) {
  __shared__ float ls[64][65];
  const int k0 = blockIdx.x * 64;
  const int c0 = blockIdx.y * 64;
  const int t = threadIdx.x;
  const int tr = t >> 6;
  const int tc = t & 63;
#pragma unroll
  for (int i = 0; i < 16; i++) {
    int k = tr * 16 + i;
    ls[k][tc] = W1[(size_t)(k0 + k) * H_DIM + c0 + tc];
  }
  __syncthreads();
#pragma unroll
  for (int i = 0; i < 16; i++) {
    int c = tr * 16 + i;
    float v = ls[tc][c];
    _Float16 hv = (_Float16)v;
    _Float16 lv = (_Float16)(v - (float)hv);
    whT[(size_t)(c0 + c) * D_DIM + k0 + tc] = hv;
    wlT[(size_t)(c0 + c) * D_DIM + k0 + tc] = lv;
  }
}

// ---------------------------------------------------------------------------
// GEMM1: h = x @ W1 via f16 hi/lo split, 16x16x32 MFMA, 256x256 tile, BK=32.
// 512 thr (8 waves 2Mx4N). A (x fp32): reg-staged, split in-register,
// swizzled ds_write into 64KB dbuf LDS (R4-verified layout, 0 conflicts).
// B (whT/wlT [col][k] f16): fragments loaded DIRECTLY global->reg, depth-1
// ping-pong (static reg sets). Barriers are raw s_barrier + lgkmcnt(0) only
// -- B global loads are NEVER drained at a barrier (no vmcnt(0) anywhere).
// R8 fix vs R7: LOAD_B k-stride is BK=32 elements per tile (was 16 -- bug).
// ---------------------------------------------------------------------------
__global__ __launch_bounds__(512, 2) void gemm1_mfma_kernel(
    const float* __restrict__ x, const _Float16* __restrict__ whT,
    const _Float16* __restrict__ wlT, float* __restrict__ h) {
  __shared__ __align__(16) char smem[65536];  // 2 x (Ah 16KB | Al 16KB)

  const int t = threadIdx.x;
  const int wave = t >> 6;
  const int lane = t & 63;

  const int bid = blockIdx.x;
  const int swz = (bid & 7) * 32 + (bid >> 3);  // XCD swizzle (256 = 8*32)
  const int by = swz >> 2, bx = swz & 3;
  const int row0 = by * 256, col0 = bx * 256;
  const int wr = wave >> 2, wc = wave & 3;  // 2x4 grid, wave tile 128x64

  floatx4 acc[8][4];
#pragma unroll
  for (int m = 0; m < 8; m++)
#pragma unroll
    for (int n = 0; n < 4; n++) acc[m][n] = (floatx4){0.f, 0.f, 0.f, 0.f};

  // ---- A reg-staging (verbatim R4, verified): unit u=(row, kslot) 8 fp32 --
  int awaddr[2];
  size_t gaoff[2];
#pragma unroll
  for (int q = 0; q < 2; q++) {
    const int u = q * 512 + t;
    const int arow = u >> 2;
    const int aslot = u & 3;
    awaddr[q] = arow * 64 + ((aslot ^ ((arow >> 1) & 3)) << 4);
    gaoff[q] = (size_t)(row0 + arow) * D_DIM + aslot * 8;
  }

  const int kg = lane >> 4;
  const int fr = lane & 15;

  // A fragment ds_read byte offsets (within 16KB array), swizzle-matched.
  int afr[8];
#pragma unroll
  for (int m = 0; m < 8; m++) {
    const int r = wr * 128 + m * 16 + fr;
    afr[m] = r * 64 + ((kg ^ ((r >> 1) & 3)) << 4);
  }

  // B fragment global element offsets ([col][k] layout; 16B/lane).
  size_t bgoff[4];
#pragma unroll
  for (int n = 0; n < 4; n++) {
    const int c = col0 + wc * 64 + n * 16 + fr;
    bgoff[n] = (size_t)c * D_DIM + kg * 8;
  }

  float4 av[2][2];
  half8 bch0[4], bcl0[4], bch1[4], bcl1[4];

#define LOAD_A(T)                                                              \
  do {                                                                         \
    const size_t kk = (size_t)(T) * 32;                                        \
    av[0][0] = *(const float4*)(x + gaoff[0] + kk);                            \
    av[0][1] = *(const float4*)(x + gaoff[0] + kk + 4);                        \
    av[1][0] = *(const float4*)(x + gaoff[1] + kk);                            \
    av[1][1] = *(const float4*)(x + gaoff[1] + kk + 4);                        \
  } while (0)

#define WRITE_A(B)                                                             \
  do {                                                                         \
    char* lb = smem + (B) * 32768;                                             \
    _Pragma("unroll") for (int q = 0; q < 2; q++) {                            \
      float vs[8] = {av[q][0].x, av[q][0].y, av[q][0].z, av[q][0].w,           \
                     av[q][1].x, av[q][1].y, av[q][1].z, av[q][1].w};          \
      half8 hh, ll;                                                            \
      _Pragma("unroll") for (int j = 0; j < 8; j++) {                          \
        _Float16 hv = (_Float16)vs[j];                                         \
        hh[j] = hv;                                                            \
        ll[j] = (_Float16)(vs[j] - (float)hv);                                 \
      }                                                                        \
      *(half8*)(lb + awaddr[q]) = hh;                                          \
      *(half8*)(lb + 16384 + awaddr[q]) = ll;                                  \
    }                                                                          \
  } while (0)

#define LOAD_B(BH, BL, T)                                                      \
  do {                                                                         \
    const size_t kk = (size_t)(T) * 32; /* BK=32 elements per K-tile */        \
    _Pragma("unroll") for (int n = 0; n < 4; n++) {                            \
      BH[n] = *(const half8*)(whT + bgoff[n] + kk);                            \
      BL[n] = *(const half8*)(wlT + bgoff[n] + kk);                            \
    }                                                                          \
  } while (0)

#define BODY(T, BCH, BCL, BNH, BNL)                                            \
  do {                                                                         \
    const char* cbase = smem + ((T) & 1) * 32768;                              \
    if ((T) < 63) {                                                            \
      LOAD_A((T) + 1);                                                         \
      LOAD_B(BNH, BNL, (T) + 1);                                               \
    }                                                                          \
    __builtin_amdgcn_sched_barrier(0);                                         \
    _Pragma("unroll") for (int m = 0; m < 8; m++) {                            \
      half8 ah = *(const half8*)(cbase + afr[m]);                              \
      half8 al = *(const half8*)(cbase + 16384 + afr[m]);                      \
      __builtin_amdgcn_s_setprio(1);                                           \
      _Pragma("unroll") for (int n = 0; n < 4; n++) {                          \
        acc[m][n] = __builtin_amdgcn_mfma_f32_16x16x32_f16(ah, BCH[n],         \
                                                           acc[m][n], 0, 0, 0);\
        acc[m][n] = __builtin_amdgcn_mfma_f32_16x16x32_f16(ah, BCL[n],         \
                                                           acc[m][n], 0, 0, 0);\
        acc[m][n] = __builtin_amdgcn_mfma_f32_16x16x32_f16(al, BCH[n],         \
                                                           acc[m][n], 0, 0, 0);\
      }                                                                        \
      __builtin_amdgcn_s_setprio(0);                                           \
    }                                                                          \
    __builtin_amdgcn_sched_barrier(0);                                         \
    if ((T) < 63) WRITE_A(((T) + 1) & 1); /* waits A-loads; B stays in flight */ \
    asm volatile("s_waitcnt lgkmcnt(0)" ::: "memory");                         \
    __builtin_amdgcn_s_barrier();                                              \
    __builtin_amdgcn_sched_barrier(0);                                         \
  } while (0)

  // ---- Prologue: tile 0 ----
  LOAD_A(0);
  LOAD_B(bch0, bcl0, 0);  // issued before WRITE_A's wait -> overlaps
  WRITE_A(0);             // compiler waits on av; B stays in flight
  asm volatile("s_waitcnt lgkmcnt(0)" ::: "memory");
  __builtin_amdgcn_s_barrier();
  __builtin_amdgcn_sched_barrier(0);

#pragma unroll 1
  for (int T2 = 0; T2 < 32; ++T2) {
    BODY(2 * T2, bch0, bcl0, bch1, bcl1);
    BODY(2 * T2 + 1, bch1, bcl1, bch0, bcl0);
  }
#undef LOAD_A
#undef WRITE_A
#undef LOAD_B
#undef BODY

  // Epilogue: C/D layout col=lane&15, row=(lane>>4)*4+j  [m89-verified]
  const int rj = (lane >> 4) * 4;
#pragma unroll
  for (int m = 0; m < 8; m++) {
    const int rbase = row0 + wr * 128 + m * 16 + rj;
#pragma unroll
    for (int n = 0; n < 4; n++) {
      const int c = col0 + wc * 64 + n * 16 + fr;
#pragma unroll
      for (int j = 0; j < 4; j++) {
        h[(size_t)(rbase + j) * H_DIM + c] = acc[m][n][j];
      }
    }
  }
}

// ---------------------------------------------------------------------------
// Kernel 2: per 8 tokens: +b1, LayerNorm, exact GELU, logits = g @ W2 + b2,
// softmax, top-2 (lower-index tie-break), renorm weights.
// ---------------------------------------------------------------------------
__device__ __forceinline__ float gelu_exact(float v) {
  return 0.5f * v * (1.0f + erff(v * 0.70710678118654752f));
}

__global__ __launch_bounds__(256) void router_kernel(
    const float* __restrict__ hbuf, const float* __restrict__ b1,
    const float* __restrict__ gamma, const float* __restrict__ beta,
    const float* __restrict__ W2, const float* __restrict__ b2,
    float* __restrict__ out) {
  __shared__ float g[8][H_DIM];
  __shared__ float w2s[128][E_DIM];
  __shared__ float lg[8][E_DIM];

  const int t = threadIdx.x;
  const int tok0 = blockIdx.x * 8;

  const int tk = t >> 5;
  const int l32 = t & 31;
  float vals[32];
  {
    const float* hr = hbuf + (size_t)(tok0 + tk) * H_DIM;
    float s = 0.f, s2 = 0.f;
#pragma unroll
    for (int q = 0; q < 8; q++) {
      const int j = q * 128 + l32 * 4;
      float4 v = *(const float4*)(hr + j);
      float4 bb = *(const float4*)(b1 + j);
      v.x += bb.x; v.y += bb.y; v.z += bb.z; v.w += bb.w;
      vals[q * 4 + 0] = v.x; vals[q * 4 + 1] = v.y;
      vals[q * 4 + 2] = v.z; vals[q * 4 + 3] = v.w;
      s += v.x + v.y + v.z + v.w;
      s2 += v.x * v.x + v.y * v.y + v.z * v.z + v.w * v.w;
    }
#pragma unroll
    for (int off = 16; off; off >>= 1) {
      s += __shfl_xor(s, off, 32);
      s2 += __shfl_xor(s2, off, 32);
    }
    const float mean = s * (1.f / 1024.f);
    const float var = s2 * (1.f / 1024.f) - mean * mean;
    const float rstd = rsqrtf(var + 1e-5f);
#pragma unroll
    for (int q = 0; q < 8; q++) {
      const int j = q * 128 + l32 * 4;
      float4 gm = *(const float4*)(gamma + j);
      float4 bt = *(const float4*)(beta + j);
      float4 o;
      o.x = gelu_exact((vals[q * 4 + 0] - mean) * rstd * gm.x + bt.x);
      o.y = gelu_exact((vals[q * 4 + 1] - mean) * rstd * gm.y + bt.y);
      o.z = gelu_exact((vals[q * 4 + 2] - mean) * rstd * gm.z + bt.z);
      o.w = gelu_exact((vals[q * 4 + 3] - mean) * rstd * gm.w + bt.w);
      *(float4*)&g[tk][j] = o;
    }
  }

  {
    float* lgf = &lg[0][0];
    lgf[t] = b2[t & 63];
    lgf[t + 256] = b2[t & 63];
  }

  const int seg = t >> 6;
  const int cell = t & 63;
  const int tp = cell >> 4;
  const int e0 = (cell & 15) * 4;

  float acc0[4] = {0.f, 0.f, 0.f, 0.f};
  float acc1[4] = {0.f, 0.f, 0.f, 0.f};

  for (int c = 0; c < 8; c++) {
    __syncthreads();
#pragma unroll
    for (int q = 0; q < 8; q++) {
      const int idx = q * 1024 + t * 4;
      *(float4*)(&w2s[0][0] + idx) = *(const float4*)(W2 + c * 8192 + idx);
    }
    __syncthreads();
#pragma unroll
    for (int q = 0; q < 8; q++) {
      const int i = seg * 32 + q * 4;
      float4 g0 = *(const float4*)&g[2 * tp][c * 128 + i];
      float4 g1 = *(const float4*)&g[2 * tp + 1][c * 128 + i];
      float4 w0 = *(const float4*)&w2s[i + 0][e0];
      float4 w1 = *(const float4*)&w2s[i + 1][e0];
      float4 w2v = *(const float4*)&w2s[i + 2][e0];
      float4 w3 = *(const float4*)&w2s[i + 3][e0];
      acc0[0] = fmaf(g0.x, w0.x, acc0[0]); acc0[1] = fmaf(g0.x, w0.y, acc0[1]);
      acc0[2] = fmaf(g0.x, w0.z, acc0[2]); acc0[3] = fmaf(g0.x, w0.w, acc0[3]);
      acc0[0] = fmaf(g0.y, w1.x, acc0[0]); acc0[1] = fmaf(g0.y, w1.y, acc0[1]);
      acc0[2] = fmaf(g0.y, w1.z, acc0[2]); acc0[3] = fmaf(g0.y, w1.w, acc0[3]);
      acc0[0] = fmaf(g0.z, w2v.x, acc0[0]); acc0[1] = fmaf(g0.z, w2v.y, acc0[1]);
      acc0[2] = fmaf(g0.z, w2v.z, acc0[2]); acc0[3] = fmaf(g0.z, w2v.w, acc0[3]);
      acc0[0] = fmaf(g0.w, w3.x, acc0[0]); acc0[1] = fmaf(g0.w, w3.y, acc0[1]);
      acc0[2] = fmaf(g0.w, w3.z, acc0[2]); acc0[3] = fmaf(g0.w, w3.w, acc0[3]);
      acc1[0] = fmaf(g1.x, w0.x, acc1[0]); acc1[1] = fmaf(g1.x, w0.y, acc1[1]);
      acc1[2] = fmaf(g1.x, w0.z, acc1[2]); acc1[3] = fmaf(g1.x, w0.w, acc1[3]);
      acc1[0] = fmaf(g1.y, w1.x, acc1[0]); acc1[1] = fmaf(g1.y, w1.y, acc1[1]);
      acc1[2] = fmaf(g1.y, w1.z, acc1[2]); acc1[3] = fmaf(g1.y, w1.w, acc1[3]);
      acc1[0] = fmaf(g1.z, w2v.x, acc1[0]); acc1[1] = fmaf(g1.z, w2v.y, acc1[1]);
      acc1[2] = fmaf(g1.z, w2v.z, acc1[2]); acc1[3] = fmaf(g1.z, w2v.w, acc1[3]);
      acc1[0] = fmaf(g1.w, w3.x, acc1[0]); acc1[1] = fmaf(g1.w, w3.y, acc1[1]);
      acc1[2] = fmaf(g1.w, w3.z, acc1[2]); acc1[3] = fmaf(g1.w, w3.w, acc1[3]);
    }
  }
#pragma unroll
  for (int j = 0; j < 4; j++) {
    atomicAdd(&lg[2 * tp][e0 + j], acc0[j]);
    atomicAdd(&lg[2 * tp + 1][e0 + j], acc1[j]);
  }
  __syncthreads();

  float* out_idx = out;
  float* out_w = out + 32768;
  float* out_logits = out + 65536;

  const int wv = t >> 6;
  const int lane = t & 63;
#pragma unroll
  for (int tt = 0; tt < 2; tt++) {
    const int tok = wv * 2 + tt;
    const int n = tok0 + tok;
    const float L = lg[tok][lane];
    float m = L;
#pragma unroll
    for (int off = 32; off; off >>= 1) m = fmaxf(m, __shfl_xor(m, off));
    const float ex = expf(L - m);
    float sum = ex;
#pragma unroll
    for (int off = 32; off; off >>= 1) sum += __shfl_xor(sum, off);
    const float p = ex / sum;

    float v1 = p; int i1 = lane;
#pragma unroll
    for (int off = 32; off; off >>= 1) {
      float ov = __shfl_xor(v1, off);
      int oi = __shfl_xor(i1, off);
      if (ov > v1 || (ov == v1 && oi < i1)) { v1 = ov; i1 = oi; }
    }
    float v2 = (lane == i1) ? -1.f : p; int i2 = lane;
#pragma unroll
    for (int off = 32; off; off >>= 1) {
      float ov = __shfl_xor(v2, off);
      int oi = __shfl_xor(i2, off);
      if (ov > v2 || (ov == v2 && oi < i2)) { v2 = ov; i2 = oi; }
    }

    out_logits[(size_t)n * 64 + lane] = L;
    if (lane == 0) {
      const float dn = v1 + v2 + 1e-9f;
      out_idx[n * 2 + 0] = (float)i1;
      out_idx[n * 2 + 1] = (float)i2;
      out_w[n * 2 + 0] = v1 / dn;
      out_w[n * 2 + 1] = v2 / dn;
    }
  }
}

extern "C" void kernel_launch(void* const* d_in, const int* in_sizes, int n_in,
                              void* d_out, int out_size, void* d_ws, size_t ws_size,
                              hipStream_t stream) {
  const float* x = (const float*)d_in[0];
  const float* W1 = (const float*)d_in[1];
  const float* b1 = (const float*)d_in[2];
  const float* gamma = (const float*)d_in[3];
  const float* beta = (const float*)d_in[4];
  const float* W2 = (const float*)d_in[5];
  const float* b2 = (const float*)d_in[6];
  float* out = (float*)d_out;

  char* ws = (char*)d_ws;
  _Float16* whT = (_Float16*)ws;                 // 4 MiB
  _Float16* wlT = (_Float16*)(ws + 4194304);     // 4 MiB
  float* hbuf = (float*)(ws + 8388608);          // 64 MiB (total 72 MiB)

  splitT_w1_kernel<<<dim3(D_DIM / 64, H_DIM / 64), 256, 0, stream>>>(W1, whT, wlT);

  gemm1_mfma_kernel<<<256, 512, 0, stream>>>(x, whT, wlT, hbuf);

  router_kernel<<<N_TOK / 8, 256, 0, stream>>>(hbuf, b1, gamma, beta, W2, b2, out);
}

// Round 9
// 292.623 us; speedup vs baseline: 1.2083x; 1.2083x over previous
//
#include <hip/hip_runtime.h>
#include <hip/hip_bf16.h>
#include <cmath>

#define N_TOK 16384
#define D_DIM 2048
#define H_DIM 1024
#define E_DIM 64

typedef _Float16 half8 __attribute__((ext_vector_type(8)));
typedef float floatx4 __attribute__((ext_vector_type(4)));

// ---------------------------------------------------------------------------
// Split W1 [2048k][1024c] -> packed MFMA-fragment-order hi/lo f16 arrays:
// pB[((kt*64 + cg)*64 + lane)*8 + j] = W1[kt*32 + (lane>>4)*8 + j][cg*16 + (lane&15)]
// so a wave's B-fragment load is one contiguous 1KB burst.
// ---------------------------------------------------------------------------
__global__ __launch_bounds__(256) void split_pack_w1_kernel(
    const float* __restrict__ W1, _Float16* __restrict__ pBh,
    _Float16* __restrict__ pBl) {
  __shared__ float ls[64][65];
  const int k0 = blockIdx.x * 64;  // 32 blocks
  const int c0 = blockIdx.y * 64;  // 16 blocks
  const int t = threadIdx.x;
  const int tr = t >> 6;
  const int tc = t & 63;
#pragma unroll
  for (int i = 0; i < 16; i++) {
    const int k = tr * 16 + i;
    ls[k][tc] = W1[(size_t)(k0 + k) * H_DIM + c0 + tc];
  }
  __syncthreads();
#pragma unroll
  for (int u0 = 0; u0 < 2; u0++) {
    const int u = u0 * 256 + t;
    const int g = u >> 6, lane = u & 63;
    const int ktl = g >> 2, cgl = g & 3;
    const int kg = lane >> 4, fr = lane & 15;
    half8 hh, ll;
#pragma unroll
    for (int j = 0; j < 8; j++) {
      const float v = ls[ktl * 32 + kg * 8 + j][cgl * 16 + fr];
      const _Float16 hv = (_Float16)v;
      hh[j] = hv;
      ll[j] = (_Float16)(v - (float)hv);
    }
    const size_t idx =
        ((((size_t)(k0 >> 5) + ktl) * 64 + (c0 >> 4) + cgl) * 64 + lane) * 8;
    *(half8*)(pBh + idx) = hh;
    *(half8*)(pBl + idx) = ll;
  }
}

// ---------------------------------------------------------------------------
// GEMM1: h = x @ W1 via f16 hi/lo split, 16x16x32 MFMA, 256x256 tile, BK=32.
// 512 thr (8 waves 2Mx4N). A (x fp32): reg-staged, split in-register,
// swizzled ds_write into 64KB dbuf LDS (R4-verified layout, 0 conflicts).
// B: PACKED fragment-order arrays, loaded direct global->reg as contiguous
// 1KB/wave bursts, depth-1 ping-pong (static reg sets). Barriers are raw
// s_barrier + lgkmcnt(0) only -- B loads never drained at a barrier.
// ---------------------------------------------------------------------------
__global__ __launch_bounds__(512, 2) void gemm1_mfma_kernel(
    const float* __restrict__ x, const _Float16* __restrict__ pBh,
    const _Float16* __restrict__ pBl, float* __restrict__ h) {
  __shared__ __align__(16) char smem[65536];  // 2 x (Ah 16KB | Al 16KB)

  const int t = threadIdx.x;
  const int wave = t >> 6;
  const int lane = t & 63;

  const int bid = blockIdx.x;
  const int swz = (bid & 7) * 32 + (bid >> 3);  // XCD swizzle (256 = 8*32)
  const int by = swz >> 2, bx = swz & 3;
  const int row0 = by * 256, col0 = bx * 256;
  const int wr = wave >> 2, wc = wave & 3;  // 2x4 grid, wave tile 128x64

  floatx4 acc[8][4];
#pragma unroll
  for (int m = 0; m < 8; m++)
#pragma unroll
    for (int n = 0; n < 4; n++) acc[m][n] = (floatx4){0.f, 0.f, 0.f, 0.f};

  // ---- A reg-staging (verbatim R4, verified): unit u=(row, kslot) 8 fp32 --
  int awaddr[2];
  size_t gaoff[2];
#pragma unroll
  for (int q = 0; q < 2; q++) {
    const int u = q * 512 + t;
    const int arow = u >> 2;
    const int aslot = u & 3;
    awaddr[q] = arow * 64 + ((aslot ^ ((arow >> 1) & 3)) << 4);
    gaoff[q] = (size_t)(row0 + arow) * D_DIM + aslot * 8;
  }

  const int kg = lane >> 4;
  const int fr = lane & 15;

  // A fragment ds_read byte offsets (within 16KB array), swizzle-matched.
  int afr[8];
#pragma unroll
  for (int m = 0; m < 8; m++) {
    const int r = wr * 128 + m * 16 + fr;
    afr[m] = r * 64 + ((kg ^ ((r >> 1) & 3)) << 4);
  }

  // B fragment offsets into packed arrays: contiguous 1KB per wave.
  const int cgbase = (col0 >> 4) + wc * 4;
  size_t bpoff[4];
#pragma unroll
  for (int n = 0; n < 4; n++) {
    bpoff[n] = ((size_t)(cgbase + n) * 64 + lane) * 8;
  }

  float4 av[2][2];
  half8 bch0[4], bcl0[4], bch1[4], bcl1[4];

#define LOAD_A(T)                                                              \
  do {                                                                         \
    const size_t kk = (size_t)(T) * 32;                                        \
    av[0][0] = *(const float4*)(x + gaoff[0] + kk);                            \
    av[0][1] = *(const float4*)(x + gaoff[0] + kk + 4);                        \
    av[1][0] = *(const float4*)(x + gaoff[1] + kk);                            \
    av[1][1] = *(const float4*)(x + gaoff[1] + kk + 4);                        \
  } while (0)

#define WRITE_A(B)                                                             \
  do {                                                                         \
    char* lb = smem + (B) * 32768;                                             \
    _Pragma("unroll") for (int q = 0; q < 2; q++) {                            \
      float vs[8] = {av[q][0].x, av[q][0].y, av[q][0].z, av[q][0].w,           \
                     av[q][1].x, av[q][1].y, av[q][1].z, av[q][1].w};          \
      half8 hh, ll;                                                            \
      _Pragma("unroll") for (int j = 0; j < 8; j++) {                          \
        _Float16 hv = (_Float16)vs[j];                                         \
        hh[j] = hv;                                                            \
        ll[j] = (_Float16)(vs[j] - (float)hv);                                 \
      }                                                                        \
      *(half8*)(lb + awaddr[q]) = hh;                                          \
      *(half8*)(lb + 16384 + awaddr[q]) = ll;                                  \
    }                                                                          \
  } while (0)

#define LOAD_B(BH, BL, T)                                                      \
  do {                                                                         \
    const size_t kk = (size_t)(T) * 32768; /* 64 cg * 64 lanes * 8 f16 */      \
    _Pragma("unroll") for (int n = 0; n < 4; n++) {                            \
      BH[n] = *(const half8*)(pBh + bpoff[n] + kk);                            \
      BL[n] = *(const half8*)(pBl + bpoff[n] + kk);                            \
    }                                                                          \
  } while (0)

#define BODY(T, BCH, BCL, BNH, BNL)                                            \
  do {                                                                         \
    const char* cbase = smem + ((T) & 1) * 32768;                              \
    if ((T) < 63) {                                                            \
      LOAD_A((T) + 1);                                                         \
      LOAD_B(BNH, BNL, (T) + 1);                                               \
    }                                                                          \
    __builtin_amdgcn_sched_barrier(0);                                         \
    _Pragma("unroll") for (int m = 0; m < 8; m++) {                            \
      half8 ah = *(const half8*)(cbase + afr[m]);                              \
      half8 al = *(const half8*)(cbase + 16384 + afr[m]);                      \
      __builtin_amdgcn_s_setprio(1);                                           \
      _Pragma("unroll") for (int n = 0; n < 4; n++) {                          \
        acc[m][n] = __builtin_amdgcn_mfma_f32_16x16x32_f16(ah, BCH[n],         \
                                                           acc[m][n], 0, 0, 0);\
        acc[m][n] = __builtin_amdgcn_mfma_f32_16x16x32_f16(ah, BCL[n],         \
                                                           acc[m][n], 0, 0, 0);\
        acc[m][n] = __builtin_amdgcn_mfma_f32_16x16x32_f16(al, BCH[n],         \
                                                           acc[m][n], 0, 0, 0);\
      }                                                                        \
      __builtin_amdgcn_s_setprio(0);                                           \
    }                                                                          \
    __builtin_amdgcn_sched_barrier(0);                                         \
    if ((T) < 63) WRITE_A(((T) + 1) & 1); /* waits A-loads; B stays in flight */ \
    asm volatile("s_waitcnt lgkmcnt(0)" ::: "memory");                         \
    __builtin_amdgcn_s_barrier();                                              \
    __builtin_amdgcn_sched_barrier(0);                                         \
  } while (0)

  // ---- Prologue: tile 0 ----
  LOAD_A(0);
  LOAD_B(bch0, bcl0, 0);  // issued before WRITE_A's wait -> overlaps
  WRITE_A(0);             // compiler waits on av; B stays in flight
  asm volatile("s_waitcnt lgkmcnt(0)" ::: "memory");
  __builtin_amdgcn_s_barrier();
  __builtin_amdgcn_sched_barrier(0);

#pragma unroll 1
  for (int T2 = 0; T2 < 32; ++T2) {
    BODY(2 * T2, bch0, bcl0, bch1, bcl1);
    BODY(2 * T2 + 1, bch1, bcl1, bch0, bcl0);
  }
#undef LOAD_A
#undef WRITE_A
#undef LOAD_B
#undef BODY

  // Epilogue: C/D layout col=lane&15, row=(lane>>4)*4+j  [m89-verified]
  const int rj = (lane >> 4) * 4;
#pragma unroll
  for (int m = 0; m < 8; m++) {
    const int rbase = row0 + wr * 128 + m * 16 + rj;
#pragma unroll
    for (int n = 0; n < 4; n++) {
      const int c = col0 + wc * 64 + n * 16 + fr;
#pragma unroll
      for (int j = 0; j < 4; j++) {
        h[(size_t)(rbase + j) * H_DIM + c] = acc[m][n][j];
      }
    }
  }
}

// ---------------------------------------------------------------------------
// Kernel 2: per 8 tokens: +b1, LayerNorm, exact GELU, logits = g @ W2 + b2,
// softmax, top-2 (lower-index tie-break), renorm weights.
// ---------------------------------------------------------------------------
__device__ __forceinline__ float gelu_exact(float v) {
  return 0.5f * v * (1.0f + erff(v * 0.70710678118654752f));
}

__global__ __launch_bounds__(256) void router_kernel(
    const float* __restrict__ hbuf, const float* __restrict__ b1,
    const float* __restrict__ gamma, const float* __restrict__ beta,
    const float* __restrict__ W2, const float* __restrict__ b2,
    float* __restrict__ out) {
  __shared__ float g[8][H_DIM];
  __shared__ float w2s[128][E_DIM];
  __shared__ float lg[8][E_DIM];

  const int t = threadIdx.x;
  const int tok0 = blockIdx.x * 8;

  const int tk = t >> 5;
  const int l32 = t & 31;
  float vals[32];
  {
    const float* hr = hbuf + (size_t)(tok0 + tk) * H_DIM;
    float s = 0.f, s2 = 0.f;
#pragma unroll
    for (int q = 0; q < 8; q++) {
      const int j = q * 128 + l32 * 4;
      float4 v = *(const float4*)(hr + j);
      float4 bb = *(const float4*)(b1 + j);
      v.x += bb.x; v.y += bb.y; v.z += bb.z; v.w += bb.w;
      vals[q * 4 + 0] = v.x; vals[q * 4 + 1] = v.y;
      vals[q * 4 + 2] = v.z; vals[q * 4 + 3] = v.w;
      s += v.x + v.y + v.z + v.w;
      s2 += v.x * v.x + v.y * v.y + v.z * v.z + v.w * v.w;
    }
#pragma unroll
    for (int off = 16; off; off >>= 1) {
      s += __shfl_xor(s, off, 32);
      s2 += __shfl_xor(s2, off, 32);
    }
    const float mean = s * (1.f / 1024.f);
    const float var = s2 * (1.f / 1024.f) - mean * mean;
    const float rstd = rsqrtf(var + 1e-5f);
#pragma unroll
    for (int q = 0; q < 8; q++) {
      const int j = q * 128 + l32 * 4;
      float4 gm = *(const float4*)(gamma + j);
      float4 bt = *(const float4*)(beta + j);
      float4 o;
      o.x = gelu_exact((vals[q * 4 + 0] - mean) * rstd * gm.x + bt.x);
      o.y = gelu_exact((vals[q * 4 + 1] - mean) * rstd * gm.y + bt.y);
      o.z = gelu_exact((vals[q * 4 + 2] - mean) * rstd * gm.z + bt.z);
      o.w = gelu_exact((vals[q * 4 + 3] - mean) * rstd * gm.w + bt.w);
      *(float4*)&g[tk][j] = o;
    }
  }

  {
    float* lgf = &lg[0][0];
    lgf[t] = b2[t & 63];
    lgf[t + 256] = b2[t & 63];
  }

  const int seg = t >> 6;
  const int cell = t & 63;
  const int tp = cell >> 4;
  const int e0 = (cell & 15) * 4;

  float acc0[4] = {0.f, 0.f, 0.f, 0.f};
  float acc1[4] = {0.f, 0.f, 0.f, 0.f};

  for (int c = 0; c < 8; c++) {
    __syncthreads();
#pragma unroll
    for (int q = 0; q < 8; q++) {
      const int idx = q * 1024 + t * 4;
      *(float4*)(&w2s[0][0] + idx) = *(const float4*)(W2 + c * 8192 + idx);
    }
    __syncthreads();
#pragma unroll
    for (int q = 0; q < 8; q++) {
      const int i = seg * 32 + q * 4;
      float4 g0 = *(const float4*)&g[2 * tp][c * 128 + i];
      float4 g1 = *(const float4*)&g[2 * tp + 1][c * 128 + i];
      float4 w0 = *(const float4*)&w2s[i + 0][e0];
      float4 w1 = *(const float4*)&w2s[i + 1][e0];
      float4 w2v = *(const float4*)&w2s[i + 2][e0];
      float4 w3 = *(const float4*)&w2s[i + 3][e0];
      acc0[0] = fmaf(g0.x, w0.x, acc0[0]); acc0[1] = fmaf(g0.x, w0.y, acc0[1]);
      acc0[2] = fmaf(g0.x, w0.z, acc0[2]); acc0[3] = fmaf(g0.x, w0.w, acc0[3]);
      acc0[0] = fmaf(g0.y, w1.x, acc0[0]); acc0[1] = fmaf(g0.y, w1.y, acc0[1]);
      acc0[2] = fmaf(g0.y, w1.z, acc0[2]); acc0[3] = fmaf(g0.y, w1.w, acc0[3]);
      acc0[0] = fmaf(g0.z, w2v.x, acc0[0]); acc0[1] = fmaf(g0.z, w2v.y, acc0[1]);
      acc0[2] = fmaf(g0.z, w2v.z, acc0[2]); acc0[3] = fmaf(g0.z, w2v.w, acc0[3]);
      acc0[0] = fmaf(g0.w, w3.x, acc0[0]); acc0[1] = fmaf(g0.w, w3.y, acc0[1]);
      acc0[2] = fmaf(g0.w, w3.z, acc0[2]); acc0[3] = fmaf(g0.w, w3.w, acc0[3]);
      acc1[0] = fmaf(g1.x, w0.x, acc1[0]); acc1[1] = fmaf(g1.x, w0.y, acc1[1]);
      acc1[2] = fmaf(g1.x, w0.z, acc1[2]); acc1[3] = fmaf(g1.x, w0.w, acc1[3]);
      acc1[0] = fmaf(g1.y, w1.x, acc1[0]); acc1[1] = fmaf(g1.y, w1.y, acc1[1]);
      acc1[2] = fmaf(g1.y, w1.z, acc1[2]); acc1[3] = fmaf(g1.y, w1.w, acc1[3]);
      acc1[0] = fmaf(g1.z, w2v.x, acc1[0]); acc1[1] = fmaf(g1.z, w2v.y, acc1[1]);
      acc1[2] = fmaf(g1.z, w2v.z, acc1[2]); acc1[3] = fmaf(g1.z, w2v.w, acc1[3]);
      acc1[0] = fmaf(g1.w, w3.x, acc1[0]); acc1[1] = fmaf(g1.w, w3.y, acc1[1]);
      acc1[2] = fmaf(g1.w, w3.z, acc1[2]); acc1[3] = fmaf(g1.w, w3.w, acc1[3]);
    }
  }
#pragma unroll
  for (int j = 0; j < 4; j++) {
    atomicAdd(&lg[2 * tp][e0 + j], acc0[j]);
    atomicAdd(&lg[2 * tp + 1][e0 + j], acc1[j]);
  }
  __syncthreads();

  float* out_idx = out;
  float* out_w = out + 32768;
  float* out_logits = out + 65536;

  const int wv = t >> 6;
  const int lane = t & 63;
#pragma unroll
  for (int tt = 0; tt < 2; tt++) {
    const int tok = wv * 2 + tt;
    const int n = tok0 + tok;
    const float L = lg[tok][lane];
    float m = L;
#pragma unroll
    for (int off = 32; off; off >>= 1) m = fmaxf(m, __shfl_xor(m, off));
    const float ex = expf(L - m);
    float sum = ex;
#pragma unroll
    for (int off = 32; off; off >>= 1) sum += __shfl_xor(sum, off);
    const float p = ex / sum;

    float v1 = p; int i1 = lane;
#pragma unroll
    for (int off = 32; off; off >>= 1) {
      float ov = __shfl_xor(v1, off);
      int oi = __shfl_xor(i1, off);
      if (ov > v1 || (ov == v1 && oi < i1)) { v1 = ov; i1 = oi; }
    }
    float v2 = (lane == i1) ? -1.f : p; int i2 = lane;
#pragma unroll
    for (int off = 32; off; off >>= 1) {
      float ov = __shfl_xor(v2, off);
      int oi = __shfl_xor(i2, off);
      if (ov > v2 || (ov == v2 && oi < i2)) { v2 = ov; i2 = oi; }
    }

    out_logits[(size_t)n * 64 + lane] = L;
    if (lane == 0) {
      const float dn = v1 + v2 + 1e-9f;
      out_idx[n * 2 + 0] = (float)i1;
      out_idx[n * 2 + 1] = (float)i2;
      out_w[n * 2 + 0] = v1 / dn;
      out_w[n * 2 + 1] = v2 / dn;
    }
  }
}

extern "C" void kernel_launch(void* const* d_in, const int* in_sizes, int n_in,
                              void* d_out, int out_size, void* d_ws, size_t ws_size,
                              hipStream_t stream) {
  const float* x = (const float*)d_in[0];
  const float* W1 = (const float*)d_in[1];
  const float* b1 = (const float*)d_in[2];
  const float* gamma = (const float*)d_in[3];
  const float* beta = (const float*)d_in[4];
  const float* W2 = (const float*)d_in[5];
  const float* b2 = (const float*)d_in[6];
  float* out = (float*)d_out;

  char* ws = (char*)d_ws;
  _Float16* pBh = (_Float16*)ws;                 // 4 MiB
  _Float16* pBl = (_Float16*)(ws + 4194304);     // 4 MiB
  float* hbuf = (float*)(ws + 8388608);          // 64 MiB (total 72 MiB)

  split_pack_w1_kernel<<<dim3(D_DIM / 64, H_DIM / 64), 256, 0, stream>>>(W1, pBh, pBl);

  gemm1_mfma_kernel<<<256, 512, 0, stream>>>(x, pBh, pBl, hbuf);

  router_kernel<<<N_TOK / 8, 256, 0, stream>>>(hbuf, b1, gamma, beta, W2, b2, out);
}